// Round 1
// baseline (188.996 us; speedup 1.0000x reference)
//
#include <hip/hip_runtime.h>
#include <hip/hip_bf16.h>

// Problem constants
#define B_   8
#define L_   128
#define S_   160
#define H_   768
#define T_   16
#define CD_  50
#define WD_  100
#define NGATE 200   // 4*CD
#define NSEQ 8      // sequences per LSTM block
#define NEGV (-1e30f)

// ---- float <-> monotonic unsigned encoding (for atomic min on floats) ----
__device__ __forceinline__ unsigned fenc(float f) {
    unsigned b = __float_as_uint(f);
    return (b & 0x80000000u) ? ~b : (b | 0x80000000u);
}
__device__ __forceinline__ float fdec(unsigned u) {
    return __uint_as_float((u & 0x80000000u) ? (u ^ 0x80000000u) : ~u);
}

__device__ __forceinline__ float sigm(float x) {
    return 1.f / (1.f + __expf(-x));
}
__device__ __forceinline__ float tanh_fast(float x) {
    float a = fabsf(x);
    float e = __expf(-2.f * a);
    float t = (1.f - e) / (1.f + e);
    return copysignf(t, x);
}

// ---------------- Kernel 1: global min of bert_emb ----------------
// 983040 elements = 960 blocks * 256 threads * 1 float4
__global__ __launch_bounds__(256) void kmin(const float* __restrict__ x, unsigned* __restrict__ wsmin) {
    int i = blockIdx.x * 256 + threadIdx.x;
    const float4* x4 = (const float4*)x;
    float4 v = x4[i];
    float m = fminf(fminf(v.x, v.y), fminf(v.z, v.w));
    __shared__ float red[256];
    red[threadIdx.x] = m;
    __syncthreads();
    for (int o = 128; o > 0; o >>= 1) {
        if (threadIdx.x < o) red[threadIdx.x] = fminf(red[threadIdx.x], red[threadIdx.x + o]);
        __syncthreads();
    }
    if (threadIdx.x == 0) atomicMin(wsmin, fenc(red[0]));
}

// ---------------- Kernel 2: transpose LSTM weights to k-major ----------------
// wT layout (floats): [mat 0..3][k2 0..24][j 0..199][2]   mat: 0=ih_f 1=hh_f 2=ih_b 3=hh_b
__global__ __launch_bounds__(256) void ktrans(const float* __restrict__ wihf, const float* __restrict__ whhf,
                                              const float* __restrict__ wihb, const float* __restrict__ whhb,
                                              float* __restrict__ wT) {
    int idx = blockIdx.x * 256 + threadIdx.x;
    if (idx >= 4 * NGATE * CD_) return;
    int m = idx / (NGATE * CD_);
    int r = idx % (NGATE * CD_);
    int j = r / CD_, k = r % CD_;
    const float* src = (m == 0) ? wihf : (m == 1) ? whhf : (m == 2) ? wihb : whhb;
    wT[m * (NGATE * CD_) + (k >> 1) * (NGATE * 2) + j * 2 + (k & 1)] = src[r];
}

// ---------------- Kernel 3: word_reps maxpool + word_embed gather + cls ----------------
__global__ __launch_bounds__(256) void kword(const float* __restrict__ bert, const int* __restrict__ p2w,
                                             const int* __restrict__ word_ids, const float* __restrict__ word_table,
                                             const unsigned* __restrict__ wsmin, float* __restrict__ out) {
    int bl = blockIdx.x;          // b*128 + l
    int b = bl >> 7;
    int l = bl & 127;
    int tid = threadIdx.x;

    __shared__ int mask[S_];
    if (tid < S_) mask[tid] = p2w[bl * S_ + tid];
    __syncthreads();

    float minv = fdec(wsmin[0]);
    float a0 = minv, a1 = minv, a2 = minv;
    const float* bb = bert + (size_t)b * S_ * H_ + tid;
    for (int s = 0; s < S_; ++s) {
        if (mask[s]) {                      // uniform branch across block
            const float* row = bb + s * H_;
            a0 = fmaxf(a0, row[0]);
            a1 = fmaxf(a1, row[256]);
            a2 = fmaxf(a2, row[512]);
        }
    }
    float* orow = out + (size_t)bl * 968;
    orow[tid] = a0; orow[tid + 256] = a1; orow[tid + 512] = a2;

    if (tid < WD_) {
        int wid = word_ids[bl];
        orow[768 + tid] = word_table[(size_t)wid * WD_ + tid];
    }
    if (l == 0) {   // cls embedding = bert_emb[b,0,:]
        const float* c = bert + (size_t)b * S_ * H_;
        float* co = out + (size_t)B_ * L_ * 968 + (size_t)b * H_;
        co[tid] = c[tid]; co[tid + 256] = c[tid + 256]; co[tid + 512] = c[tid + 512];
    }
}

// ---------------- Kernel 4: BiLSTM + fused masked max-pool over T ----------------
// grid = 256 blocks: blockIdx.x&1 = direction, blockIdx.x>>1 = seq group (8 seqs each)
__global__ __launch_bounds__(256) void klstm(const int* __restrict__ char_ids, const int* __restrict__ char_count,
                                             const int* __restrict__ tok_mask, const float* __restrict__ char_table,
                                             const float* __restrict__ b_f, const float* __restrict__ b_b,
                                             const float* __restrict__ wT, float* __restrict__ out) {
    int dir = blockIdx.x & 1;
    int grp = blockIdx.x >> 1;
    int tid = threadIdx.x;

    __shared__ __align__(16) float xbuf[NSEQ][CD_];
    __shared__ __align__(16) float hbuf[NSEQ][CD_];
    __shared__ __align__(16) float gbuf[NSEQ][NGATE];
    __shared__ int cid[NSEQ][T_];
    __shared__ int slen[NSEQ];
    __shared__ int smask[NSEQ];

    for (int idx = tid; idx < NSEQ * T_; idx += 256) {
        int s = idx >> 4, t = idx & 15;
        cid[s][t] = char_ids[(grp * NSEQ + s) * T_ + t];
    }
    if (tid < NSEQ) {
        int n = grp * NSEQ + tid;
        int c = char_count[n];
        slen[tid] = (c > 0) ? c : 1;
        int mb = 0;
        for (int t = 0; t < T_; ++t) mb |= (tok_mask[n * T_ + t] != 0) << t;
        smask[tid] = mb;
    }
    for (int idx = tid; idx < NSEQ * CD_; idx += 256) hbuf[idx / CD_][idx % CD_] = 0.f;

    const float2* wih2 = (const float2*)(wT + (dir ? 2 : 0) * (NGATE * CD_));
    const float2* whh2 = (const float2*)(wT + (dir ? 3 : 1) * (NGATE * CD_));
    float bj = 0.f;
    if (tid < NGATE) bj = (dir ? b_b : b_f)[tid];

    int cell = tid % CD_;
    int sb = tid / CD_;            // 0..3 for active threads
    float creg[2] = {0.f, 0.f};
    float mreg[2] = {NEGV, NEGV};

    __syncthreads();

    for (int t = 0; t < T_; ++t) {
        // stage x_t (reversed + zero-padded for backward direction)
        for (int idx = tid; idx < NSEQ * CD_; idx += 256) {
            int s = idx / CD_, k = idx % CD_;
            int st = dir ? (slen[s] - 1 - t) : t;
            float xv = 0.f;
            if (st >= 0) xv = char_table[cid[s][st] * CD_ + k];
            xbuf[s][k] = xv;
        }
        __syncthreads();

        // gate phase: thread j computes gate j for all NSEQ sequences
        if (tid < NGATE) {
            float acc[NSEQ];
#pragma unroll
            for (int s = 0; s < NSEQ; ++s) acc[s] = bj;
#pragma unroll 5
            for (int k2 = 0; k2 < CD_ / 2; ++k2) {
                float2 wv = wih2[k2 * NGATE + tid];
#pragma unroll
                for (int s = 0; s < NSEQ; ++s) {
                    float2 xv = *(const float2*)&xbuf[s][k2 * 2];
                    acc[s] = fmaf(wv.x, xv.x, acc[s]);
                    acc[s] = fmaf(wv.y, xv.y, acc[s]);
                }
            }
#pragma unroll 5
            for (int k2 = 0; k2 < CD_ / 2; ++k2) {
                float2 wv = whh2[k2 * NGATE + tid];
#pragma unroll
                for (int s = 0; s < NSEQ; ++s) {
                    float2 hv = *(const float2*)&hbuf[s][k2 * 2];
                    acc[s] = fmaf(wv.x, hv.x, acc[s]);
                    acc[s] = fmaf(wv.y, hv.y, acc[s]);
                }
            }
#pragma unroll
            for (int s = 0; s < NSEQ; ++s) gbuf[s][tid] = acc[s];
        }
        __syncthreads();

        // update phase: thread handles cell for seqs {sb, sb+4}; fused pool max
        if (tid < NGATE) {
#pragma unroll
            for (int p = 0; p < 2; ++p) {
                int s = sb + 4 * p;
                float gi = gbuf[s][cell];
                float gf = gbuf[s][cell + CD_];
                float gg = gbuf[s][cell + 2 * CD_];
                float go = gbuf[s][cell + 3 * CD_];
                float cc = creg[p];
                cc = sigm(gf) * cc + sigm(gi) * tanh_fast(gg);
                float h = sigm(go) * tanh_fast(cc);
                creg[p] = cc;
                hbuf[s][cell] = h;
                int tt = dir ? (slen[s] - 1 - t) : t;   // position in original time order
                if (tt >= 0 && ((smask[s] >> tt) & 1)) mreg[p] = fmaxf(mreg[p], h);
            }
        }
        __syncthreads();
    }

    if (tid < NGATE) {
#pragma unroll
        for (int p = 0; p < 2; ++p) {
            int s = sb + 4 * p;
            float m = mreg[p];
            // backward half: masked positions at t >= len contribute h_bwd = 0
            if (dir && (smask[s] >> slen[s])) m = fmaxf(m, 0.f);
            if (m == NEGV) m = 0.f;
            out[(size_t)(grp * NSEQ + s) * 968 + 868 + dir * CD_ + cell] = m;
        }
    }
}

extern "C" void kernel_launch(void* const* d_in, const int* in_sizes, int n_in,
                              void* d_out, int out_size, void* d_ws, size_t ws_size,
                              hipStream_t stream) {
    const float* bert       = (const float*)d_in[0];
    const int*   p2w        = (const int*)d_in[1];
    const int*   word_ids   = (const int*)d_in[2];
    const int*   char_ids   = (const int*)d_in[3];
    const int*   char_count = (const int*)d_in[4];
    const int*   tok_mask   = (const int*)d_in[5];
    const float* word_table = (const float*)d_in[6];
    const float* char_table = (const float*)d_in[7];
    const float* w_ih_f = (const float*)d_in[8];
    const float* w_hh_f = (const float*)d_in[9];
    const float* b_f    = (const float*)d_in[10];
    const float* w_ih_b = (const float*)d_in[11];
    const float* w_hh_b = (const float*)d_in[12];
    const float* b_b    = (const float*)d_in[13];

    float*    out   = (float*)d_out;
    unsigned* wsmin = (unsigned*)d_ws;
    float*    wT    = (float*)((char*)d_ws + 256);

    hipMemsetAsync(d_ws, 0xFF, 4, stream);                       // init min slot to +max enc
    kmin  <<<960, 256, 0, stream>>>(bert, wsmin);
    ktrans<<<(4 * NGATE * CD_ + 255) / 256, 256, 0, stream>>>(w_ih_f, w_hh_f, w_ih_b, w_hh_b, wT);
    kword <<<B_ * L_, 256, 0, stream>>>(bert, p2w, word_ids, word_table, wsmin, out);
    klstm <<<(B_ * L_ / NSEQ) * 2, 256, 0, stream>>>(char_ids, char_count, tok_mask, char_table,
                                                     b_f, b_b, wT, out);
}

// Round 2
// 126.715 us; speedup vs baseline: 1.4915x; 1.4915x over previous
//
#include <hip/hip_runtime.h>
#include <hip/hip_bf16.h>

// Problem constants
#define B_   8
#define L_   128
#define S_   160
#define H_   768
#define T_   16
#define CD_  50
#define WD_  100
#define NGATE 200   // 4*CD
#define NSEQ 8      // sequences per LSTM block
#define NEGV (-1e30f)

// ---- float <-> monotonic unsigned encoding (for atomic min on floats) ----
__device__ __forceinline__ unsigned fenc(float f) {
    unsigned b = __float_as_uint(f);
    return (b & 0x80000000u) ? ~b : (b | 0x80000000u);
}
__device__ __forceinline__ float fdec(unsigned u) {
    return __uint_as_float((u & 0x80000000u) ? (u ^ 0x80000000u) : ~u);
}

__device__ __forceinline__ float sigm(float x) {
    return __fdividef(1.f, 1.f + __expf(-x));
}
__device__ __forceinline__ float tanh_fast(float x) {
    float a = fabsf(x);
    float e = __expf(-2.f * a);
    float t = __fdividef(1.f - e, 1.f + e);
    return copysignf(t, x);
}

// ---------------- Kernel 1: global min of bert_emb ----------------
// 983040 elements = 960 blocks * 256 threads * 1 float4
__global__ __launch_bounds__(256) void kmin(const float* __restrict__ x, unsigned* __restrict__ wsmin) {
    int i = blockIdx.x * 256 + threadIdx.x;
    const float4* x4 = (const float4*)x;
    float4 v = x4[i];
    float m = fminf(fminf(v.x, v.y), fminf(v.z, v.w));
    __shared__ float red[256];
    red[threadIdx.x] = m;
    __syncthreads();
    for (int o = 128; o > 0; o >>= 1) {
        if (threadIdx.x < o) red[threadIdx.x] = fminf(red[threadIdx.x], red[threadIdx.x + o]);
        __syncthreads();
    }
    if (threadIdx.x == 0) atomicMin(wsmin, fenc(red[0]));
}

// ---------------- Kernel 2: word_reps maxpool + word_embed gather + cls ----------------
__global__ __launch_bounds__(256) void kword(const float* __restrict__ bert, const int* __restrict__ p2w,
                                             const int* __restrict__ word_ids, const float* __restrict__ word_table,
                                             const unsigned* __restrict__ wsmin, float* __restrict__ out) {
    int bl = blockIdx.x;          // b*128 + l
    int b = bl >> 7;
    int l = bl & 127;
    int tid = threadIdx.x;

    __shared__ int mask[S_];
    if (tid < S_) mask[tid] = p2w[bl * S_ + tid];
    __syncthreads();

    float minv = fdec(wsmin[0]);
    float a0 = minv, a1 = minv, a2 = minv;
    const float* bb = bert + (size_t)b * S_ * H_ + tid;
    for (int s = 0; s < S_; ++s) {
        if (mask[s]) {                      // uniform branch across block
            const float* row = bb + s * H_;
            a0 = fmaxf(a0, row[0]);
            a1 = fmaxf(a1, row[256]);
            a2 = fmaxf(a2, row[512]);
        }
    }
    float* orow = out + (size_t)bl * 968;
    orow[tid] = a0; orow[tid + 256] = a1; orow[tid + 512] = a2;

    if (tid < WD_) {
        int wid = word_ids[bl];
        orow[768 + tid] = word_table[(size_t)wid * WD_ + tid];
    }
    if (l == 0) {   // cls embedding = bert_emb[b,0,:]
        const float* c = bert + (size_t)b * S_ * H_;
        float* co = out + (size_t)B_ * L_ * 968 + (size_t)b * H_;
        co[tid] = c[tid]; co[tid + 256] = c[tid + 256]; co[tid + 512] = c[tid + 512];
    }
}

// ---------------- Kernel 3: BiLSTM + fused masked max-pool over T ----------------
// grid = 256 blocks: blockIdx.x&1 = direction, blockIdx.x>>1 = seq group (8 seqs each)
// Weight-stationary: gate thread j holds w_ih[j][:], w_hh[j][:] in 100 VGPRs.
// x staged for ALL 16 steps up-front in [t][k][s] layout -> gate loop reads are
// uniform-address float4 LDS broadcasts (conflict-free).
__global__ __launch_bounds__(256, 1) void klstm(const int* __restrict__ char_ids, const int* __restrict__ char_count,
                                                const int* __restrict__ tok_mask, const float* __restrict__ char_table,
                                                const float* __restrict__ w_ih_f, const float* __restrict__ w_hh_f,
                                                const float* __restrict__ b_f,
                                                const float* __restrict__ w_ih_b, const float* __restrict__ w_hh_b,
                                                const float* __restrict__ b_b,
                                                float* __restrict__ out) {
    int dir = blockIdx.x & 1;
    int grp = blockIdx.x >> 1;
    int tid = threadIdx.x;

    __shared__ __align__(16) float xall[T_][CD_][NSEQ];   // 25600 B
    __shared__ __align__(16) float hbuf[CD_][NSEQ];       // 1600 B
    __shared__ __align__(16) float gbuf[NSEQ][NGATE];     // 6400 B
    __shared__ int cid[NSEQ][T_];
    __shared__ int slen[NSEQ];
    __shared__ int smask[NSEQ];

    for (int idx = tid; idx < NSEQ * T_; idx += 256) {
        int s = idx >> 4, t = idx & 15;
        cid[s][t] = char_ids[(grp * NSEQ + s) * T_ + t];
    }
    if (tid < NSEQ) {
        int n = grp * NSEQ + tid;
        int c = char_count[n];
        slen[tid] = (c > 0) ? c : 1;
        int mb = 0;
        for (int t = 0; t < T_; ++t) mb |= (tok_mask[n * T_ + t] != 0) << t;
        smask[tid] = mb;
    }
    __syncthreads();

    // stage x for all timesteps (reversed + zero-padded for backward dir)
    for (int idx = tid; idx < T_ * CD_ * NSEQ; idx += 256) {
        int s = idx & 7;
        int k = (idx >> 3) % CD_;
        int t = idx / (CD_ * NSEQ);
        int st = dir ? (slen[s] - 1 - t) : t;
        float xv = 0.f;
        if (st >= 0) xv = char_table[cid[s][st] * CD_ + k];
        xall[t][k][s] = xv;
    }
    for (int idx = tid; idx < CD_ * NSEQ; idx += 256) hbuf[idx >> 3][idx & 7] = 0.f;

    // weight-stationary register load (rows are contiguous in the original layout)
    float wihr[CD_], whhr[CD_];
    float bj = 0.f;
    if (tid < NGATE) {
        const float* wih = dir ? w_ih_b : w_ih_f;
        const float* whh = dir ? w_hh_b : w_hh_f;
#pragma unroll
        for (int k2 = 0; k2 < CD_ / 2; ++k2) {
            float2 a = *(const float2*)(wih + tid * CD_ + 2 * k2);
            wihr[2 * k2] = a.x; wihr[2 * k2 + 1] = a.y;
            float2 b2 = *(const float2*)(whh + tid * CD_ + 2 * k2);
            whhr[2 * k2] = b2.x; whhr[2 * k2 + 1] = b2.y;
        }
        bj = (dir ? b_b : b_f)[tid];
    }
    __syncthreads();

    int cell = tid % CD_;
    int sb = tid / CD_;            // 0..3 for active threads
    float creg[2] = {0.f, 0.f};
    float mreg[2] = {NEGV, NEGV};

#pragma unroll 1
    for (int t = 0; t < T_; ++t) {
        if (tid < NGATE) {
            float acc[NSEQ];
#pragma unroll
            for (int s = 0; s < NSEQ; ++s) acc[s] = bj;
            const float* xk = &xall[t][0][0];
#pragma unroll
            for (int k = 0; k < CD_; ++k) {
                float4 xa = *(const float4*)(xk + k * NSEQ);
                float4 xb = *(const float4*)(xk + k * NSEQ + 4);
                float w = wihr[k];
                acc[0] = fmaf(w, xa.x, acc[0]); acc[1] = fmaf(w, xa.y, acc[1]);
                acc[2] = fmaf(w, xa.z, acc[2]); acc[3] = fmaf(w, xa.w, acc[3]);
                acc[4] = fmaf(w, xb.x, acc[4]); acc[5] = fmaf(w, xb.y, acc[5]);
                acc[6] = fmaf(w, xb.z, acc[6]); acc[7] = fmaf(w, xb.w, acc[7]);
            }
#pragma unroll
            for (int k = 0; k < CD_; ++k) {
                float4 ha = *(const float4*)(&hbuf[k][0]);
                float4 hb = *(const float4*)(&hbuf[k][4]);
                float w = whhr[k];
                acc[0] = fmaf(w, ha.x, acc[0]); acc[1] = fmaf(w, ha.y, acc[1]);
                acc[2] = fmaf(w, ha.z, acc[2]); acc[3] = fmaf(w, ha.w, acc[3]);
                acc[4] = fmaf(w, hb.x, acc[4]); acc[5] = fmaf(w, hb.y, acc[5]);
                acc[6] = fmaf(w, hb.z, acc[6]); acc[7] = fmaf(w, hb.w, acc[7]);
            }
#pragma unroll
            for (int s = 0; s < NSEQ; ++s) gbuf[s][tid] = acc[s];
        }
        __syncthreads();

        if (tid < NGATE) {
#pragma unroll
            for (int p = 0; p < 2; ++p) {
                int s = sb + 4 * p;
                float gi = gbuf[s][cell];
                float gf = gbuf[s][cell + CD_];
                float gg = gbuf[s][cell + 2 * CD_];
                float go = gbuf[s][cell + 3 * CD_];
                float cc = creg[p];
                cc = sigm(gf) * cc + sigm(gi) * tanh_fast(gg);
                float h = sigm(go) * tanh_fast(cc);
                creg[p] = cc;
                hbuf[cell][s] = h;
                int tt = dir ? (slen[s] - 1 - t) : t;   // position in original time order
                if (tt >= 0 && ((smask[s] >> tt) & 1)) mreg[p] = fmaxf(mreg[p], h);
            }
        }
        __syncthreads();
    }

    if (tid < NGATE) {
#pragma unroll
        for (int p = 0; p < 2; ++p) {
            int s = sb + 4 * p;
            float m = mreg[p];
            // backward half: masked positions at t >= len contribute h_bwd = 0
            if (dir && (smask[s] >> slen[s])) m = fmaxf(m, 0.f);
            if (m == NEGV) m = 0.f;
            out[(size_t)(grp * NSEQ + s) * 968 + 868 + dir * CD_ + cell] = m;
        }
    }
}

extern "C" void kernel_launch(void* const* d_in, const int* in_sizes, int n_in,
                              void* d_out, int out_size, void* d_ws, size_t ws_size,
                              hipStream_t stream) {
    const float* bert       = (const float*)d_in[0];
    const int*   p2w        = (const int*)d_in[1];
    const int*   word_ids   = (const int*)d_in[2];
    const int*   char_ids   = (const int*)d_in[3];
    const int*   char_count = (const int*)d_in[4];
    const int*   tok_mask   = (const int*)d_in[5];
    const float* word_table = (const float*)d_in[6];
    const float* char_table = (const float*)d_in[7];
    const float* w_ih_f = (const float*)d_in[8];
    const float* w_hh_f = (const float*)d_in[9];
    const float* b_f    = (const float*)d_in[10];
    const float* w_ih_b = (const float*)d_in[11];
    const float* w_hh_b = (const float*)d_in[12];
    const float* b_b    = (const float*)d_in[13];

    float*    out   = (float*)d_out;
    unsigned* wsmin = (unsigned*)d_ws;

    hipMemsetAsync(d_ws, 0xFF, 4, stream);                       // init min slot to +max enc
    kmin  <<<960, 256, 0, stream>>>(bert, wsmin);
    kword <<<B_ * L_, 256, 0, stream>>>(bert, p2w, word_ids, word_table, wsmin, out);
    klstm <<<(B_ * L_ / NSEQ) * 2, 256, 0, stream>>>(char_ids, char_count, tok_mask, char_table,
                                                     w_ih_f, w_hh_f, b_f, w_ih_b, w_hh_b, b_b, out);
}